// Round 3
// baseline (683.152 us; speedup 1.0000x reference)
//
#include <hip/hip_runtime.h>
#include <hip/hip_bf16.h>

// Problem constants (match reference setup_inputs)
#define NSETS 8
#define NPTS  4096
#define DF    16
#define KNN   16
#define QPB   64                  // queries per block (one per lane)
#define NCH   4                   // candidate chunks per query (one per wave)
#define BLK   (QPB * NCH)         // 256 threads
#define CHUNK (NPTS / NCH)        // 1024 candidates per lane
#define NEDGE (NSETS * NPTS * KNN)

// d_out layout (decoded as FLOAT32 by the harness — established round 2 from
// absmax=18431 signature): [src (524288 f32) | dst (524288 f32) | dist (524288 f32)]
__global__ __launch_bounds__(BLK) void knn_kernel(const float* __restrict__ x,
                                                  float* __restrict__ out) {
    __shared__ float nrm[NPTS];          // 16 KB: all candidate norms for this set
    __shared__ float lds_d[BLK * KNN];   // 16 KB: per-(query,chunk) top-16 dists
    __shared__ int   lds_i[BLK * KNN];   // 16 KB: per-(query,chunk) top-16 ids

    const int t    = threadIdx.x;
    const int lane = t & 63;
    const int wv   = t >> 6;                    // chunk index 0..3
    const int set  = blockIdx.x >> 6;           // 64 blocks per set
    const int q0   = (blockIdx.x & 63) * QPB;
    const int q    = q0 + lane;                 // this lane's query point

    const float* xs = x + (size_t)set * NPTS * DF;

    // ---- Phase A: all 4096 candidate norms -> LDS --------------------------
    for (int r = 0; r < NPTS / BLK; ++r) {
        const int c = r * BLK + t;
        const float4* p = (const float4*)(xs + (size_t)c * DF);
        float4 a = p[0], b = p[1], g = p[2], d = p[3];
        float r0 = __fadd_rn(__fmul_rn(a.x, a.x), __fmul_rn(g.x, g.x));
        float r1 = __fadd_rn(__fmul_rn(a.y, a.y), __fmul_rn(g.y, g.y));
        float r2 = __fadd_rn(__fmul_rn(a.z, a.z), __fmul_rn(g.z, g.z));
        float r3 = __fadd_rn(__fmul_rn(a.w, a.w), __fmul_rn(g.w, g.w));
        float r4 = __fadd_rn(__fmul_rn(b.x, b.x), __fmul_rn(d.x, d.x));
        float r5 = __fadd_rn(__fmul_rn(b.y, b.y), __fmul_rn(d.y, d.y));
        float r6 = __fadd_rn(__fmul_rn(b.z, b.z), __fmul_rn(d.z, d.z));
        float r7 = __fadd_rn(__fmul_rn(b.w, b.w), __fmul_rn(d.w, d.w));
        nrm[c] = __fadd_rn(
            __fadd_rn(__fadd_rn(r0, r1), __fadd_rn(r2, r3)),
            __fadd_rn(__fadd_rn(r4, r5), __fadd_rn(r6, r7)));
    }
    __syncthreads();

    // ---- Phase B: scan this wave's candidate chunk -------------------------
    float qf[DF];
    {
        const float4* qp = (const float4*)(xs + (size_t)q * DF);
        float4 v0 = qp[0], v1 = qp[1], v2 = qp[2], v3 = qp[3];
        qf[0]=v0.x; qf[1]=v0.y; qf[2]=v0.z; qf[3]=v0.w;
        qf[4]=v1.x; qf[5]=v1.y; qf[6]=v1.z; qf[7]=v1.w;
        qf[8]=v2.x; qf[9]=v2.y; qf[10]=v2.z; qf[11]=v2.w;
        qf[12]=v3.x; qf[13]=v3.y; qf[14]=v3.z; qf[15]=v3.w;
    }
    const float q2 = nrm[q];   // identical bits to the candidate-side norm

    // Sorted ascending top-16: strict-< insertion => stable tie-break by
    // ascending candidate index (matches lax.top_k).
    float Ld[KNN];
    int   Li[KNN];
#pragma unroll
    for (int j = 0; j < KNN; ++j) { Ld[j] = 3.0e38f; Li[j] = 0; }

    const int cb = __builtin_amdgcn_readfirstlane(wv * CHUNK);

    for (int i = 0; i < CHUNK; ++i) {
        const int c = cb + i;
        const float* cf = xs + (size_t)c * DF;   // wave-uniform -> scalar loads
        float dot = 0.f;
#pragma unroll
        for (int d = 0; d < DF; ++d) dot = fmaf(qf[d], cf[d], dot);
        const float dist = __fsub_rn(__fadd_rn(q2, nrm[c]),
                                     __fmul_rn(2.0f, dot));

        if (dist < Ld[KNN - 1]) {
#pragma unroll
            for (int j = KNN - 1; j >= 1; --j) {
                const bool sh   = dist < Ld[j - 1];   // element shifts down
                const bool here = dist < Ld[j];       // new value lands here
                const float nd = sh ? Ld[j - 1] : (here ? dist : Ld[j]);
                const int   ni = sh ? Li[j - 1] : (here ? c    : Li[j]);
                Ld[j] = nd; Li[j] = ni;
            }
            if (dist < Ld[0]) { Ld[0] = dist; Li[0] = c; }
        }
    }

    // ---- Phase C: merge the 4 per-chunk lists and emit ---------------------
#pragma unroll
    for (int j = 0; j < KNN; ++j) {
        lds_d[t * KNN + j] = Ld[j];
        lds_i[t * KNN + j] = Li[j];
    }
    __syncthreads();

    if (t < QPB) {
        const int l = t;
        float h[NCH];
        int   p[NCH];
#pragma unroll
        for (int w2 = 0; w2 < NCH; ++w2) {
            p[w2] = 0;
            h[w2] = lds_d[(w2 * QPB + l) * KNN];
        }

        const int    gq = set * NPTS + q0 + l;
        const size_t eb = (size_t)gq * KNN;
        float* osrc = out;
        float* odst = out + (size_t)NEDGE;
        float* odis = out + 2 * (size_t)NEDGE;
        const float srcf = (float)gq;

        for (int e = 0; e < KNN; ++e) {
            float best = h[0];
            int   bw   = 0;
#pragma unroll
            for (int w2 = 1; w2 < NCH; ++w2)
                if (h[w2] < best) { best = h[w2]; bw = w2; }   // strict < :
                                                               // ties -> lowest
                                                               // chunk -> lowest id
            int li = 0;
#pragma unroll
            for (int w2 = 0; w2 < NCH; ++w2) {
                if (bw == w2) {
                    li = lds_i[(w2 * QPB + l) * KNN + p[w2]];
                    ++p[w2];
                    h[w2] = (p[w2] < KNN) ? lds_d[(w2 * QPB + l) * KNN + p[w2]]
                                          : 3.0e38f;
                }
            }

            osrc[eb + e] = srcf;
            odst[eb + e] = (float)(set * NPTS + li);
            odis[eb + e] = best;
        }
    }
}

// ---------------------------------------------------------------------------
extern "C" void kernel_launch(void* const* d_in, const int* in_sizes, int n_in,
                              void* d_out, int out_size, void* d_ws, size_t ws_size,
                              hipStream_t stream) {
    (void)in_sizes; (void)n_in; (void)out_size; (void)d_ws; (void)ws_size;
    const float* x = (const float*)d_in[0];  // (8, 4096, 16) f32
    float* out = (float*)d_out;              // [src|dst|dist] f32

    knn_kernel<<<NSETS * (NPTS / QPB), BLK, 0, stream>>>(x, out);
}

// Round 4
// 283.626 us; speedup vs baseline: 2.4086x; 2.4086x over previous
//
#include <hip/hip_runtime.h>
#include <hip/hip_bf16.h>

// Problem constants (match reference setup_inputs)
#define NSETS 8
#define NPTS  4096
#define DF    16
#define KNN   16
#define QPB   64                  // queries per block (one per lane)
#define NCH   4                   // candidate chunks per query (one per wave)
#define BLK   (QPB * NCH)         // 256 threads
#define CHUNK (NPTS / NCH)        // 1024 candidates per lane
#define NEDGE (NSETS * NPTS * KNN)

// Deferred-selection reservoir (round 3: the 16-deep guarded insert fired on
// ~100% of iterations due to 64-lane wave correlation -> 75 of ~95 VALU/iter
// wasted; measured model matched 645us). Scan now appends (dist,idx) survivors
// vs stale tau to a per-lane LDS FIFO; exact strict-< insert replayed only at
// flushes (ascending idx order -> final lists bit-identical to round 3).
#define RES      23               // reservoir slots/lane (max cnt = 15+GRP = 23)
#define FLUSH_AT 16               // flush when any lane cnt >= this
#define GRP      8                // candidates between flush checks

__global__ __launch_bounds__(BLK) void knn_kernel(const float* __restrict__ x,
                                                  float* __restrict__ out) {
    __shared__ float nrm[NPTS];                          // 16 KB, live whole kernel
    __shared__ __align__(16) char smem[RES * BLK * 8];   // 46 KB reservoir; merge overlay
    float2* resv  = (float2*)smem;                       // resv[slot*BLK + t]
    float*  lds_d = (float*)smem;                        // overlay after final flush
    int*    lds_i = (int*)(smem + BLK * KNN * 4);

    const int t    = threadIdx.x;
    const int lane = t & 63;
    const int wv   = t >> 6;                    // chunk index 0..3
    const int set  = blockIdx.x >> 6;           // 64 blocks per set
    const int q0   = (blockIdx.x & 63) * QPB;
    const int q    = q0 + lane;                 // this lane's query point

    const float* xs = x + (size_t)set * NPTS * DF;

    // ---- Phase A: all 4096 candidate norms -> LDS (bit-identical to r3) ----
    for (int r = 0; r < NPTS / BLK; ++r) {
        const int c = r * BLK + t;
        const float4* p = (const float4*)(xs + (size_t)c * DF);
        float4 a = p[0], b = p[1], g = p[2], d = p[3];
        float r0 = __fadd_rn(__fmul_rn(a.x, a.x), __fmul_rn(g.x, g.x));
        float r1 = __fadd_rn(__fmul_rn(a.y, a.y), __fmul_rn(g.y, g.y));
        float r2 = __fadd_rn(__fmul_rn(a.z, a.z), __fmul_rn(g.z, g.z));
        float r3 = __fadd_rn(__fmul_rn(a.w, a.w), __fmul_rn(g.w, g.w));
        float r4 = __fadd_rn(__fmul_rn(b.x, b.x), __fmul_rn(d.x, d.x));
        float r5 = __fadd_rn(__fmul_rn(b.y, b.y), __fmul_rn(d.y, d.y));
        float r6 = __fadd_rn(__fmul_rn(b.z, b.z), __fmul_rn(d.z, d.z));
        float r7 = __fadd_rn(__fmul_rn(b.w, b.w), __fmul_rn(d.w, d.w));
        nrm[c] = __fadd_rn(
            __fadd_rn(__fadd_rn(r0, r1), __fadd_rn(r2, r3)),
            __fadd_rn(__fadd_rn(r4, r5), __fadd_rn(r6, r7)));
    }
    __syncthreads();

    // ---- Phase B: scan this wave's candidate chunk -------------------------
    float qf[DF];
    {
        const float4* qp = (const float4*)(xs + (size_t)q * DF);
        float4 v0 = qp[0], v1 = qp[1], v2 = qp[2], v3 = qp[3];
        qf[0]=v0.x; qf[1]=v0.y; qf[2]=v0.z; qf[3]=v0.w;
        qf[4]=v1.x; qf[5]=v1.y; qf[6]=v1.z; qf[7]=v1.w;
        qf[8]=v2.x; qf[9]=v2.y; qf[10]=v2.z; qf[11]=v2.w;
        qf[12]=v3.x; qf[13]=v3.y; qf[14]=v3.z; qf[15]=v3.w;
    }
    const float q2 = nrm[q];

    float Ld[KNN];
    int   Li[KNN];
#pragma unroll
    for (int j = 0; j < KNN; ++j) { Ld[j] = 3.0e38f; Li[j] = 0; }
    float tau = 3.0e38f;
    int   cnt = 0;

    const int cb = __builtin_amdgcn_readfirstlane(wv * CHUNK);

    // Exact drain: replay strict-< shift-insert in append (ascending idx)
    // order. Unwritten/stale slots masked to +BIG via (e < cnt).
    auto flush = [&]() {
        for (int e = 0; e < RES; ++e) {
            if (!__any(e < cnt)) break;
            float2 en = resv[e * BLK + t];
            const float d  = (e < cnt) ? en.x : 3.0e38f;
            const int   ci = __float_as_int(en.y);
            if (d < Ld[KNN - 1]) {
#pragma unroll
                for (int j = KNN - 1; j >= 1; --j) {
                    const bool sh   = d < Ld[j - 1];
                    const bool here = d < Ld[j];
                    const float nd = sh ? Ld[j - 1] : (here ? d  : Ld[j]);
                    const int   ni = sh ? Li[j - 1] : (here ? ci : Li[j]);
                    Ld[j] = nd; Li[j] = ni;
                }
                if (d < Ld[0]) { Ld[0] = d; Li[0] = ci; }
            }
        }
        cnt = 0;
        tau = Ld[KNN - 1];   // fresh conservative filter threshold
    };

    for (int g = 0; g < CHUNK; g += GRP) {
#pragma unroll
        for (int u = 0; u < GRP; ++u) {
            const int c = cb + g + u;
            const float* cf = xs + (size_t)c * DF;   // wave-uniform -> scalar loads
            float dot = 0.f;
#pragma unroll
            for (int d = 0; d < DF; ++d) dot = fmaf(qf[d], cf[d], dot);
            const float dist = __fsub_rn(__fadd_rn(q2, nrm[c]),
                                         __fmul_rn(2.0f, dot));
            if (dist < tau) {                        // cheap predicated append
                resv[cnt * BLK + t] = make_float2(dist, __int_as_float(c));
                ++cnt;
            }
        }
        if (__any(cnt >= FLUSH_AT)) flush();         // rare, wave-uniform
    }
    flush();                                          // final drain

    // ---- Phase C: merge the 4 per-chunk lists and emit ---------------------
    __syncthreads();   // all reservoir reads done before overlay writes
#pragma unroll
    for (int j = 0; j < KNN; ++j) {
        lds_d[t * KNN + j] = Ld[j];
        lds_i[t * KNN + j] = Li[j];
    }
    __syncthreads();

    if (t < QPB) {
        const int l = t;
        float h[NCH];
        int   p[NCH];
#pragma unroll
        for (int w2 = 0; w2 < NCH; ++w2) {
            p[w2] = 0;
            h[w2] = lds_d[(w2 * QPB + l) * KNN];
        }

        const int    gq = set * NPTS + q0 + l;
        const size_t eb = (size_t)gq * KNN;
        float* osrc = out;
        float* odst = out + (size_t)NEDGE;
        float* odis = out + 2 * (size_t)NEDGE;
        const float srcf = (float)gq;

        for (int e = 0; e < KNN; ++e) {
            float best = h[0];
            int   bw   = 0;
#pragma unroll
            for (int w2 = 1; w2 < NCH; ++w2)
                if (h[w2] < best) { best = h[w2]; bw = w2; }   // ties -> lowest chunk

            int li = 0;
#pragma unroll
            for (int w2 = 0; w2 < NCH; ++w2) {
                if (bw == w2) {
                    li = lds_i[(w2 * QPB + l) * KNN + p[w2]];
                    ++p[w2];
                    h[w2] = (p[w2] < KNN) ? lds_d[(w2 * QPB + l) * KNN + p[w2]]
                                          : 3.0e38f;
                }
            }

            osrc[eb + e] = srcf;
            odst[eb + e] = (float)(set * NPTS + li);
            odis[eb + e] = best;
        }
    }
}

// ---------------------------------------------------------------------------
extern "C" void kernel_launch(void* const* d_in, const int* in_sizes, int n_in,
                              void* d_out, int out_size, void* d_ws, size_t ws_size,
                              hipStream_t stream) {
    (void)in_sizes; (void)n_in; (void)out_size; (void)d_ws; (void)ws_size;
    const float* x = (const float*)d_in[0];  // (8, 4096, 16) f32
    float* out = (float*)d_out;              // [src|dst|dist] f32

    knn_kernel<<<NSETS * (NPTS / QPB), BLK, 0, stream>>>(x, out);
}

// Round 5
// 259.818 us; speedup vs baseline: 2.6294x; 1.0916x over previous
//
#include <hip/hip_runtime.h>
#include <hip/hip_bf16.h>

// Problem constants (match reference setup_inputs)
#define NSETS 8
#define NPTS  4096
#define DF    16
#define KNN   16
#define QPB   64                  // queries per block (one per lane)
#define NCH   8                   // candidate chunks per query (one per wave)
#define BLK   (QPB * NCH)         // 512 threads, 8 waves
#define CHUNK (NPTS / NCH)        // 512 candidates per lane
#define NEDGE (NSETS * NPTS * KNN)

// Round-5 restructure: r4 was latency-bound (VALUBusy 52%, 2 waves/SIMD, grid
// = exactly 2 blocks/CU). Same total work now spread over 8 waves/block ->
// 16 waves/CU (4/SIMD) to hide s_load/ds latency. Distance math + strict-<
// index-ordered selection + lowest-chunk tie-break bit-identical to r4.
#define RES      15               // reservoir slots/lane (max cnt = 11+GRP = 15)
#define FLUSH_AT 12               // flush when any lane cnt >= this
#define GRP      4                // candidates between flush checks

__global__ __launch_bounds__(BLK) void knn_kernel(const float* __restrict__ x,
                                                  float* __restrict__ out) {
    __shared__ float nrm[NPTS];                          // 16 KB, live whole kernel
    __shared__ __align__(16) char smem[RES * BLK * 8];   // 60 KB reservoir
    float2*         resv  = (float2*)smem;               // resv[slot*BLK + t]
    float*          lds_d = (float*)smem;                // overlay after last flush
    unsigned short* lds_i = (unsigned short*)(smem + BLK * KNN * 4);
    // total static LDS = 16384 + 61440 = 77824 B -> 2 blocks/CU (155648<=163840)

    const int t    = threadIdx.x;
    const int lane = t & 63;
    const int wv   = t >> 6;                    // chunk index 0..7
    const int set  = blockIdx.x >> 6;           // 64 blocks per set
    const int q0   = (blockIdx.x & 63) * QPB;
    const int q    = q0 + lane;                 // this lane's query point

    const float* xs = x + (size_t)set * NPTS * DF;

    // ---- Phase A: all 4096 candidate norms -> LDS (bit-identical to r3) ----
    for (int r = 0; r < NPTS / BLK; ++r) {
        const int c = r * BLK + t;
        const float4* p = (const float4*)(xs + (size_t)c * DF);
        float4 a = p[0], b = p[1], g = p[2], d = p[3];
        float r0 = __fadd_rn(__fmul_rn(a.x, a.x), __fmul_rn(g.x, g.x));
        float r1 = __fadd_rn(__fmul_rn(a.y, a.y), __fmul_rn(g.y, g.y));
        float r2 = __fadd_rn(__fmul_rn(a.z, a.z), __fmul_rn(g.z, g.z));
        float r3 = __fadd_rn(__fmul_rn(a.w, a.w), __fmul_rn(g.w, g.w));
        float r4 = __fadd_rn(__fmul_rn(b.x, b.x), __fmul_rn(d.x, d.x));
        float r5 = __fadd_rn(__fmul_rn(b.y, b.y), __fmul_rn(d.y, d.y));
        float r6 = __fadd_rn(__fmul_rn(b.z, b.z), __fmul_rn(d.z, d.z));
        float r7 = __fadd_rn(__fmul_rn(b.w, b.w), __fmul_rn(d.w, d.w));
        nrm[c] = __fadd_rn(
            __fadd_rn(__fadd_rn(r0, r1), __fadd_rn(r2, r3)),
            __fadd_rn(__fadd_rn(r4, r5), __fadd_rn(r6, r7)));
    }
    __syncthreads();

    // ---- Phase B: scan this wave's candidate chunk -------------------------
    float qf[DF];
    {
        const float4* qp = (const float4*)(xs + (size_t)q * DF);
        float4 v0 = qp[0], v1 = qp[1], v2 = qp[2], v3 = qp[3];
        qf[0]=v0.x; qf[1]=v0.y; qf[2]=v0.z; qf[3]=v0.w;
        qf[4]=v1.x; qf[5]=v1.y; qf[6]=v1.z; qf[7]=v1.w;
        qf[8]=v2.x; qf[9]=v2.y; qf[10]=v2.z; qf[11]=v2.w;
        qf[12]=v3.x; qf[13]=v3.y; qf[14]=v3.z; qf[15]=v3.w;
    }
    const float q2 = nrm[q];

    float Ld[KNN];
    int   Li[KNN];
#pragma unroll
    for (int j = 0; j < KNN; ++j) { Ld[j] = 3.0e38f; Li[j] = 0; }
    float tau = 3.0e38f;
    int   cnt = 0;

    const int cb = __builtin_amdgcn_readfirstlane(wv * CHUNK);

    // Exact drain: replay strict-< shift-insert in append (ascending idx)
    // order. Unwritten/stale slots masked to +BIG via (e < cnt).
    auto flush = [&]() {
        for (int e = 0; e < RES; ++e) {
            if (!__any(e < cnt)) break;
            float2 en = resv[e * BLK + t];
            const float d  = (e < cnt) ? en.x : 3.0e38f;
            const int   ci = __float_as_int(en.y);
            if (d < Ld[KNN - 1]) {
#pragma unroll
                for (int j = KNN - 1; j >= 1; --j) {
                    const bool sh   = d < Ld[j - 1];
                    const bool here = d < Ld[j];
                    const float nd = sh ? Ld[j - 1] : (here ? d  : Ld[j]);
                    const int   ni = sh ? Li[j - 1] : (here ? ci : Li[j]);
                    Ld[j] = nd; Li[j] = ni;
                }
                if (d < Ld[0]) { Ld[0] = d; Li[0] = ci; }
            }
        }
        cnt = 0;
        tau = Ld[KNN - 1];   // fresh conservative filter threshold
    };

    for (int g = 0; g < CHUNK; g += GRP) {
#pragma unroll
        for (int u = 0; u < GRP; ++u) {
            const int c = cb + g + u;
            const float* cf = xs + (size_t)c * DF;   // wave-uniform -> scalar loads
            float dot = 0.f;
#pragma unroll
            for (int d = 0; d < DF; ++d) dot = fmaf(qf[d], cf[d], dot);
            const float dist = __fsub_rn(__fadd_rn(q2, nrm[c]),
                                         __fmul_rn(2.0f, dot));
            if (dist < tau) {                        // cheap predicated append
                resv[cnt * BLK + t] = make_float2(dist, __int_as_float(c));
                ++cnt;
            }
        }
        if (__any(cnt >= FLUSH_AT)) flush();         // rare, wave-uniform
    }
    flush();                                          // final drain

    // ---- Phase C: merge the 8 per-chunk lists and emit ---------------------
    __syncthreads();   // overlay region aliases other threads' reservoir slots
#pragma unroll
    for (int j = 0; j < KNN; ++j) {
        lds_d[t * KNN + j] = Ld[j];
        lds_i[t * KNN + j] = (unsigned short)Li[j];
    }
    __syncthreads();

    if (t < QPB) {
        const int l = t;
        float h[NCH];
        int   p[NCH];
#pragma unroll
        for (int w2 = 0; w2 < NCH; ++w2) {
            p[w2] = 0;
            h[w2] = lds_d[(w2 * QPB + l) * KNN];
        }

        const int    gq = set * NPTS + q0 + l;
        const size_t eb = (size_t)gq * KNN;
        float* osrc = out;
        float* odst = out + (size_t)NEDGE;
        float* odis = out + 2 * (size_t)NEDGE;
        const float srcf = (float)gq;

        for (int e = 0; e < KNN; ++e) {
            float best = h[0];
            int   bw   = 0;
#pragma unroll
            for (int w2 = 1; w2 < NCH; ++w2)
                if (h[w2] < best) { best = h[w2]; bw = w2; }   // ties -> lowest
                                                               // chunk -> lowest id
            int li = 0;
#pragma unroll
            for (int w2 = 0; w2 < NCH; ++w2) {
                if (bw == w2) {
                    li = (int)lds_i[(w2 * QPB + l) * KNN + p[w2]];
                    ++p[w2];
                    h[w2] = (p[w2] < KNN) ? lds_d[(w2 * QPB + l) * KNN + p[w2]]
                                          : 3.0e38f;
                }
            }

            osrc[eb + e] = srcf;
            odst[eb + e] = (float)(set * NPTS + li);
            odis[eb + e] = best;
        }
    }
}

// ---------------------------------------------------------------------------
extern "C" void kernel_launch(void* const* d_in, const int* in_sizes, int n_in,
                              void* d_out, int out_size, void* d_ws, size_t ws_size,
                              hipStream_t stream) {
    (void)in_sizes; (void)n_in; (void)out_size; (void)d_ws; (void)ws_size;
    const float* x = (const float*)d_in[0];  // (8, 4096, 16) f32
    float* out = (float*)d_out;              // [src|dst|dist] f32

    knn_kernel<<<NSETS * (NPTS / QPB), BLK, 0, stream>>>(x, out);
}

// Round 6
// 241.758 us; speedup vs baseline: 2.8258x; 1.0747x over previous
//
#include <hip/hip_runtime.h>
#include <hip/hip_bf16.h>

// Problem constants (match reference setup_inputs)
#define NSETS 8
#define NPTS  4096
#define DF    16
#define KNN   16
#define QPB   64                  // queries per block (one per lane)
#define NCH   8                   // candidate chunks per query (one per wave)
#define BLK   (QPB * NCH)         // 512 threads, 8 waves
#define CHUNK (NPTS / NCH)        // 512 candidates per lane
#define NEDGE (NSETS * NPTS * KNN)

// Round-6: block-shared tau. r5 showed selection overhead (append bursts +
// 85-instr flush replays) at ~3x the dot-product floor because each wave kept
// an independent tau over its 512-candidate chunk. All 8 waves serve the SAME
// 64 queries -> publish each wave's running 16th into tau_sh[query] (benign
// race: every written value is a valid conservative bound >= global 16th).
// Filter is non-strict (d <= tau) so cross-chunk boundary ties are retained;
// local insert + merge keep r5's exact index-stable semantics.
#define RES      15               // reservoir slots/lane (max cnt = 11+GRP = 15)
#define FLUSH_AT 12               // flush when any lane cnt >= this
#define GRP      4                // candidates between flush checks

__global__ __launch_bounds__(BLK) void knn_kernel(const float* __restrict__ x,
                                                  float* __restrict__ out) {
    __shared__ float nrm[NPTS];                          // 16 KB, live whole kernel
    __shared__ float tau_sh[QPB];                        // shared per-query tau
    __shared__ __align__(16) char smem[RES * BLK * 8];   // 60 KB reservoir
    float2*         resv  = (float2*)smem;               // resv[slot*BLK + t]
    float*          lds_d = (float*)smem;                // overlay after last flush
    unsigned short* lds_i = (unsigned short*)(smem + BLK * KNN * 4);

    const int t    = threadIdx.x;
    const int lane = t & 63;
    const int wv   = t >> 6;                    // chunk index 0..7
    const int set  = blockIdx.x >> 6;           // 64 blocks per set
    const int q0   = (blockIdx.x & 63) * QPB;
    const int q    = q0 + lane;                 // this lane's query point

    const float* xs = x + (size_t)set * NPTS * DF;

    if (t < QPB) tau_sh[t] = 3.0e38f;

    // ---- Phase A: all 4096 candidate norms -> LDS (bit-identical to r3) ----
    for (int r = 0; r < NPTS / BLK; ++r) {
        const int c = r * BLK + t;
        const float4* p = (const float4*)(xs + (size_t)c * DF);
        float4 a = p[0], b = p[1], g = p[2], d = p[3];
        float r0 = __fadd_rn(__fmul_rn(a.x, a.x), __fmul_rn(g.x, g.x));
        float r1 = __fadd_rn(__fmul_rn(a.y, a.y), __fmul_rn(g.y, g.y));
        float r2 = __fadd_rn(__fmul_rn(a.z, a.z), __fmul_rn(g.z, g.z));
        float r3 = __fadd_rn(__fmul_rn(a.w, a.w), __fmul_rn(g.w, g.w));
        float r4 = __fadd_rn(__fmul_rn(b.x, b.x), __fmul_rn(d.x, d.x));
        float r5 = __fadd_rn(__fmul_rn(b.y, b.y), __fmul_rn(d.y, d.y));
        float r6 = __fadd_rn(__fmul_rn(b.z, b.z), __fmul_rn(d.z, d.z));
        float r7 = __fadd_rn(__fmul_rn(b.w, b.w), __fmul_rn(d.w, d.w));
        nrm[c] = __fadd_rn(
            __fadd_rn(__fadd_rn(r0, r1), __fadd_rn(r2, r3)),
            __fadd_rn(__fadd_rn(r4, r5), __fadd_rn(r6, r7)));
    }
    __syncthreads();

    // ---- Phase B: scan this wave's candidate chunk -------------------------
    // qn[d] = -2 * q_d. Exact power-of-2 scaling commutes with fma rounding:
    // sum of fma(-2*q_d, c_d) == -2 * (fma chain of q_d*c_d) bitwise, so
    // dist = (q2+nc) + dot' is bit-identical to r3's (q2+nc) - 2*dot.
    float qn[DF];
    {
        const float4* qp = (const float4*)(xs + (size_t)q * DF);
        float4 v0 = qp[0], v1 = qp[1], v2 = qp[2], v3 = qp[3];
        qn[0]=v0.x; qn[1]=v0.y; qn[2]=v0.z; qn[3]=v0.w;
        qn[4]=v1.x; qn[5]=v1.y; qn[6]=v1.z; qn[7]=v1.w;
        qn[8]=v2.x; qn[9]=v2.y; qn[10]=v2.z; qn[11]=v2.w;
        qn[12]=v3.x; qn[13]=v3.y; qn[14]=v3.z; qn[15]=v3.w;
    }
    const float q2 = nrm[q];
#pragma unroll
    for (int d = 0; d < DF; ++d) qn[d] = -2.0f * qn[d];   // exact

    float Ld[KNN];
    int   Li[KNN];
#pragma unroll
    for (int j = 0; j < KNN; ++j) { Ld[j] = 3.0e38f; Li[j] = 0; }
    int cnt = 0;

    const int cb = __builtin_amdgcn_readfirstlane(wv * CHUNK);

    // Exact drain: replay strict-< shift-insert in append (ascending idx)
    // order, then publish my running 16th to the shared per-query tau.
    auto flush = [&]() {
        for (int e = 0; e < RES; ++e) {
            if (!__any(e < cnt)) break;
            float2 en = resv[e * BLK + t];
            const float d  = (e < cnt) ? en.x : 3.0e38f;
            const int   ci = __float_as_int(en.y);
            if (d < Ld[KNN - 1]) {
#pragma unroll
                for (int j = KNN - 1; j >= 1; --j) {
                    const bool sh   = d < Ld[j - 1];
                    const bool here = d < Ld[j];
                    const float nd = sh ? Ld[j - 1] : (here ? d  : Ld[j]);
                    const int   ni = sh ? Li[j - 1] : (here ? ci : Li[j]);
                    Ld[j] = nd; Li[j] = ni;
                }
                if (d < Ld[0]) { Ld[0] = d; Li[0] = ci; }
            }
        }
        cnt = 0;
        // Benign-race conservative min across the 8 waves of this block.
        volatile float* ts = (volatile float*)tau_sh;
        float cur = ts[lane];
        ts[lane] = fminf(cur, Ld[KNN - 1]);
    };

    for (int g = 0; g < CHUNK; g += GRP) {
        const float tsh = ((volatile float*)tau_sh)[lane];
        const float tau = fminf(tsh, Ld[KNN - 1]);
#pragma unroll
        for (int u = 0; u < GRP; ++u) {
            const int c = cb + g + u;
            const float* cf = xs + (size_t)c * DF;   // wave-uniform -> scalar loads
            float dot = 0.f;
#pragma unroll
            for (int d = 0; d < DF; ++d) dot = fmaf(qn[d], cf[d], dot);
            const float dist = __fadd_rn(__fadd_rn(q2, nrm[c]), dot);
            if (dist <= tau) {                       // non-strict: keep boundary
                resv[cnt * BLK + t] = make_float2(dist, __int_as_float(c));
                ++cnt;                               // ties across chunks
            }
        }
        if (__any(cnt >= FLUSH_AT)) flush();         // rare once tau is live
    }
    flush();                                          // final drain

    // ---- Phase C: merge the 8 per-chunk lists and emit ---------------------
    __syncthreads();   // overlay region aliases other threads' reservoir slots
#pragma unroll
    for (int j = 0; j < KNN; ++j) {
        lds_d[t * KNN + j] = Ld[j];
        lds_i[t * KNN + j] = (unsigned short)Li[j];
    }
    __syncthreads();

    if (t < QPB) {
        const int l = t;
        float h[NCH];
        int   p[NCH];
#pragma unroll
        for (int w2 = 0; w2 < NCH; ++w2) {
            p[w2] = 0;
            h[w2] = lds_d[(w2 * QPB + l) * KNN];
        }

        const int    gq = set * NPTS + q0 + l;
        const size_t eb = (size_t)gq * KNN;
        float* osrc = out;
        float* odst = out + (size_t)NEDGE;
        float* odis = out + 2 * (size_t)NEDGE;
        const float srcf = (float)gq;

        for (int e = 0; e < KNN; ++e) {
            float best = h[0];
            int   bw   = 0;
#pragma unroll
            for (int w2 = 1; w2 < NCH; ++w2)
                if (h[w2] < best) { best = h[w2]; bw = w2; }   // ties -> lowest
                                                               // chunk -> lowest id
            int li = 0;
#pragma unroll
            for (int w2 = 0; w2 < NCH; ++w2) {
                if (bw == w2) {
                    li = (int)lds_i[(w2 * QPB + l) * KNN + p[w2]];
                    ++p[w2];
                    h[w2] = (p[w2] < KNN) ? lds_d[(w2 * QPB + l) * KNN + p[w2]]
                                          : 3.0e38f;
                }
            }

            osrc[eb + e] = srcf;
            odst[eb + e] = (float)(set * NPTS + li);
            odis[eb + e] = best;
        }
    }
}

// ---------------------------------------------------------------------------
extern "C" void kernel_launch(void* const* d_in, const int* in_sizes, int n_in,
                              void* d_out, int out_size, void* d_ws, size_t ws_size,
                              hipStream_t stream) {
    (void)in_sizes; (void)n_in; (void)out_size; (void)d_ws; (void)ws_size;
    const float* x = (const float*)d_in[0];  // (8, 4096, 16) f32
    float* out = (float*)d_out;              // [src|dst|dist] f32

    knn_kernel<<<NSETS * (NPTS / QPB), BLK, 0, stream>>>(x, out);
}

// Round 7
// 229.182 us; speedup vs baseline: 2.9808x; 1.0549x over previous
//
#include <hip/hip_runtime.h>
#include <hip/hip_bf16.h>

// Problem constants (match reference setup_inputs)
#define NSETS 8
#define NPTS  4096
#define DF    16
#define KNN   16
#define QPB   64                  // queries per block (one per lane)
#define NCH   8                   // waves per block
#define BLK   (QPB * NCH)         // 512 threads
#define TILE  512                 // candidates staged into LDS per tile
#define NTILE (NPTS / TILE)       // 8
#define SLICE (TILE / NCH)        // 64 candidates per wave per tile
#define NEDGE (NSETS * NPTS * KNN)

// Round-7: r6 analysis showed per-SIMD VALU util ~20%; the stall is the
// candidate feature fetch — 8 distinct s_load streams/CU thrash the scalar L1
// and every group waits ~200cyc on L2 (SGPR budget caps lookahead). Fix:
// cooperative LDS tile staging; scans read candidates via wave-uniform
// ds_read_b128 broadcast. Wave slices are strided -> merge tie-break is now
// explicit (dist, idx) lexicographic (== reference stable-top-k order).
#define RES      8                // reservoir slots/lane (max cnt = 4+GRP = 8)
#define FLUSH_AT 5                // flush when any lane cnt >= this
#define GRP      4                // candidates between flush checks

#define FEAT_B   (TILE * DF * 4)            // 32768 B: feat4[4][TILE] transposed
#define NRM_B    (TILE * 4)                 // 2048 B:  nrm_t[TILE]
#define RESV_OFF (FEAT_B + NRM_B)           // 34816
#define SMEM_B   (RESV_OFF + RES * BLK * 8) // 67584 B -> 2 blocks/CU

__global__ __launch_bounds__(BLK) void knn_kernel(const float* __restrict__ x,
                                                  float* __restrict__ out) {
    __shared__ float tau_sh[QPB];                 // shared per-query tau
    __shared__ __align__(16) char smem[SMEM_B];
    float4* feat4 = (float4*)smem;                // feat4[r*TILE + c], r=0..3
    float*  nrm_t = (float*)(smem + FEAT_B);      // candidate norms
    float2* resv  = (float2*)(smem + RESV_OFF);   // resv[slot*BLK + t]
    float*          lds_d = (float*)smem;                    // overlay (post-scan)
    unsigned short* lds_i = (unsigned short*)(smem + BLK * KNN * 4);

    const int t    = threadIdx.x;
    const int lane = t & 63;
    const int wv   = t >> 6;                    // slice index 0..7
    const int set  = blockIdx.x >> 6;           // 64 blocks per set
    const int q0   = (blockIdx.x & 63) * QPB;
    const int q    = q0 + lane;                 // this lane's query point

    const float* xs = x + (size_t)set * NPTS * DF;

    if (t < QPB) tau_sh[t] = 3.0e38f;

    // Query features; q2 via the SAME pairwise tree as candidate norms (bit-
    // identical to r3's Phase A formula). qn = -2*q: exact pow2 scaling
    // commutes with fma rounding -> dist bit-identical to r3.
    float qn[DF];
    float q2;
    {
        const float4* qp = (const float4*)(xs + (size_t)q * DF);
        float4 a = qp[0], b = qp[1], g = qp[2], d = qp[3];
        float r0 = __fadd_rn(__fmul_rn(a.x, a.x), __fmul_rn(g.x, g.x));
        float r1 = __fadd_rn(__fmul_rn(a.y, a.y), __fmul_rn(g.y, g.y));
        float r2 = __fadd_rn(__fmul_rn(a.z, a.z), __fmul_rn(g.z, g.z));
        float r3 = __fadd_rn(__fmul_rn(a.w, a.w), __fmul_rn(g.w, g.w));
        float r4 = __fadd_rn(__fmul_rn(b.x, b.x), __fmul_rn(d.x, d.x));
        float r5 = __fadd_rn(__fmul_rn(b.y, b.y), __fmul_rn(d.y, d.y));
        float r6 = __fadd_rn(__fmul_rn(b.z, b.z), __fmul_rn(d.z, d.z));
        float r7 = __fadd_rn(__fmul_rn(b.w, b.w), __fmul_rn(d.w, d.w));
        q2 = __fadd_rn(__fadd_rn(__fadd_rn(r0, r1), __fadd_rn(r2, r3)),
                       __fadd_rn(__fadd_rn(r4, r5), __fadd_rn(r6, r7)));
        qn[0]=a.x; qn[1]=a.y; qn[2]=a.z; qn[3]=a.w;
        qn[4]=b.x; qn[5]=b.y; qn[6]=b.z; qn[7]=b.w;
        qn[8]=g.x; qn[9]=g.y; qn[10]=g.z; qn[11]=g.w;
        qn[12]=d.x; qn[13]=d.y; qn[14]=d.z; qn[15]=d.w;
#pragma unroll
        for (int d2 = 0; d2 < DF; ++d2) qn[d2] = -2.0f * qn[d2];
    }

    float Ld[KNN];
    int   Li[KNN];
#pragma unroll
    for (int j = 0; j < KNN; ++j) { Ld[j] = 3.0e38f; Li[j] = 0; }
    int cnt = 0;

    // Exact drain: replay strict-< shift-insert in append (ascending idx)
    // order, then publish my running 16th to the shared per-query tau.
    auto flush = [&]() {
        for (int e = 0; e < RES; ++e) {
            if (!__any(e < cnt)) break;
            float2 en = resv[e * BLK + t];
            const float d  = (e < cnt) ? en.x : 3.0e38f;
            const int   ci = __float_as_int(en.y);
            if (d < Ld[KNN - 1]) {
#pragma unroll
                for (int j = KNN - 1; j >= 1; --j) {
                    const bool sh   = d < Ld[j - 1];
                    const bool here = d < Ld[j];
                    const float nd = sh ? Ld[j - 1] : (here ? d  : Ld[j]);
                    const int   ni = sh ? Li[j - 1] : (here ? ci : Li[j]);
                    Ld[j] = nd; Li[j] = ni;
                }
                if (d < Ld[0]) { Ld[0] = d; Li[0] = ci; }
            }
        }
        cnt = 0;
        volatile float* ts = (volatile float*)tau_sh;   // benign-race cons. min
        float cur = ts[lane];
        ts[lane] = fminf(cur, Ld[KNN - 1]);
    };

    for (int tile = 0; tile < NTILE; ++tile) {
        __syncthreads();   // previous tile fully consumed (also covers tau init)
        {
            // Thread t stages candidate tile*TILE+t: features (transposed
            // float4 rows) + norm via the exact Phase-A tree, in registers.
            const int c = tile * TILE + t;
            const float4* p = (const float4*)(xs + (size_t)c * DF);
            float4 a = p[0], b = p[1], g = p[2], d = p[3];
            float r0 = __fadd_rn(__fmul_rn(a.x, a.x), __fmul_rn(g.x, g.x));
            float r1 = __fadd_rn(__fmul_rn(a.y, a.y), __fmul_rn(g.y, g.y));
            float r2 = __fadd_rn(__fmul_rn(a.z, a.z), __fmul_rn(g.z, g.z));
            float r3 = __fadd_rn(__fmul_rn(a.w, a.w), __fmul_rn(g.w, g.w));
            float r4 = __fadd_rn(__fmul_rn(b.x, b.x), __fmul_rn(d.x, d.x));
            float r5 = __fadd_rn(__fmul_rn(b.y, b.y), __fmul_rn(d.y, d.y));
            float r6 = __fadd_rn(__fmul_rn(b.z, b.z), __fmul_rn(d.z, d.z));
            float r7 = __fadd_rn(__fmul_rn(b.w, b.w), __fmul_rn(d.w, d.w));
            feat4[0 * TILE + t] = a;
            feat4[1 * TILE + t] = b;
            feat4[2 * TILE + t] = g;
            feat4[3 * TILE + t] = d;
            nrm_t[t] = __fadd_rn(
                __fadd_rn(__fadd_rn(r0, r1), __fadd_rn(r2, r3)),
                __fadd_rn(__fadd_rn(r4, r5), __fadd_rn(r6, r7)));
        }
        __syncthreads();

        const int lbase = wv * SLICE;            // local slice base in tile
        const int gbase = tile * TILE + lbase;   // global candidate id base

        for (int g = 0; g < SLICE; g += GRP) {
            const float tsh = ((volatile float*)tau_sh)[lane];
            const float tau = fminf(tsh, Ld[KNN - 1]);
#pragma unroll
            for (int u = 0; u < GRP; ++u) {
                const int lc = lbase + g + u;    // wave-uniform -> broadcast
                float4 f0 = feat4[0 * TILE + lc];
                float4 f1 = feat4[1 * TILE + lc];
                float4 f2 = feat4[2 * TILE + lc];
                float4 f3 = feat4[3 * TILE + lc];
                const float nc = nrm_t[lc];
                float dot = 0.f;
                dot = fmaf(qn[0],  f0.x, dot); dot = fmaf(qn[1],  f0.y, dot);
                dot = fmaf(qn[2],  f0.z, dot); dot = fmaf(qn[3],  f0.w, dot);
                dot = fmaf(qn[4],  f1.x, dot); dot = fmaf(qn[5],  f1.y, dot);
                dot = fmaf(qn[6],  f1.z, dot); dot = fmaf(qn[7],  f1.w, dot);
                dot = fmaf(qn[8],  f2.x, dot); dot = fmaf(qn[9],  f2.y, dot);
                dot = fmaf(qn[10], f2.z, dot); dot = fmaf(qn[11], f2.w, dot);
                dot = fmaf(qn[12], f3.x, dot); dot = fmaf(qn[13], f3.y, dot);
                dot = fmaf(qn[14], f3.z, dot); dot = fmaf(qn[15], f3.w, dot);
                const float dist = __fadd_rn(__fadd_rn(q2, nc), dot);
                if (dist <= tau) {               // non-strict: keep boundary ties
                    resv[cnt * BLK + t] =
                        make_float2(dist, __int_as_float(gbase + g + u));
                    ++cnt;
                }
            }
            if (__any(cnt >= FLUSH_AT)) flush();
        }
    }
    flush();                                      // final drain

    // ---- Merge the 8 per-slice lists and emit ------------------------------
    __syncthreads();   // overlay aliases tile + other threads' reservoir slots
#pragma unroll
    for (int j = 0; j < KNN; ++j) {
        lds_d[t * KNN + j] = Ld[j];
        lds_i[t * KNN + j] = (unsigned short)Li[j];
    }
    __syncthreads();

    if (t < QPB) {
        const int l = t;
        float h[NCH];
        int   hi[NCH];
        int   p[NCH];
#pragma unroll
        for (int w2 = 0; w2 < NCH; ++w2) {
            p[w2]  = 0;
            h[w2]  = lds_d[(w2 * QPB + l) * KNN];
            hi[w2] = (int)lds_i[(w2 * QPB + l) * KNN];
        }

        const int    gq = set * NPTS + q0 + l;
        const size_t eb = (size_t)gq * KNN;
        float* osrc = out;
        float* odst = out + (size_t)NEDGE;
        float* odis = out + 2 * (size_t)NEDGE;
        const float srcf = (float)gq;

        for (int e = 0; e < KNN; ++e) {
            // (dist, idx) lexicographic min across the 8 heads — exact stable
            // top-k order (slices are strided, so idx must break ties).
            float best = h[0];
            int   bi   = hi[0];
            int   bw   = 0;
#pragma unroll
            for (int w2 = 1; w2 < NCH; ++w2) {
                const bool better = (h[w2] < best) ||
                                    (h[w2] == best && hi[w2] < bi);
                if (better) { best = h[w2]; bi = hi[w2]; bw = w2; }
            }

#pragma unroll
            for (int w2 = 0; w2 < NCH; ++w2) {
                if (bw == w2) {
                    ++p[w2];
                    if (p[w2] < KNN) {
                        h[w2]  = lds_d[(w2 * QPB + l) * KNN + p[w2]];
                        hi[w2] = (int)lds_i[(w2 * QPB + l) * KNN + p[w2]];
                    } else {
                        h[w2]  = 3.0e38f;
                        hi[w2] = 0x7FFFFFFF;
                    }
                }
            }

            osrc[eb + e] = srcf;
            odst[eb + e] = (float)(set * NPTS + bi);
            odis[eb + e] = best;
        }
    }
}

// ---------------------------------------------------------------------------
extern "C" void kernel_launch(void* const* d_in, const int* in_sizes, int n_in,
                              void* d_out, int out_size, void* d_ws, size_t ws_size,
                              hipStream_t stream) {
    (void)in_sizes; (void)n_in; (void)out_size; (void)d_ws; (void)ws_size;
    const float* x = (const float*)d_in[0];  // (8, 4096, 16) f32
    float* out = (float*)d_out;              // [src|dst|dist] f32

    knn_kernel<<<NSETS * (NPTS / QPB), BLK, 0, stream>>>(x, out);
}